// Round 13
// baseline (401.317 us; speedup 1.0000x reference)
//
#include <hip/hip_runtime.h>

#define HH 64

typedef __attribute__((ext_vector_type(8))) short bf16x8;
typedef __attribute__((ext_vector_type(16))) float f32x16;
typedef __attribute__((ext_vector_type(4))) unsigned uintx4;

__device__ __forceinline__ unsigned short f2bf(float f) {
  unsigned u = __builtin_bit_cast(unsigned, f);
  return (unsigned short)((u + 0x7FFFu + ((u >> 16) & 1u)) >> 16);
}
__device__ __forceinline__ float bf2f(unsigned short h) {
  unsigned u = ((unsigned)h) << 16;
  return __builtin_bit_cast(float, u);
}
__device__ __forceinline__ unsigned pk2bf(float lo, float hi) {
  unsigned r;
  asm("v_cvt_pk_bf16_f32 %0, %1, %2" : "=v"(r) : "v"(lo), "v"(hi));
  return r;
}

// ---------- prep: Wvo = Wo@Wv, bvo = Wo@bv + bo, B-packs ----------
// EVEN/ODD pack: n = 2*(ln&31) + t ; k = s*16 + (ln>>5)*8 + e8
__global__ __launch_bounds__(256) void k_prep(
    const float* __restrict__ Wg1, const float* __restrict__ Wg2,
    const float* __restrict__ Wnh, const float* __restrict__ Wo,
    const float* __restrict__ Wv,  const float* __restrict__ bv,
    const float* __restrict__ bo,  const float* __restrict__ We2,
    float* __restrict__ Wvo, float* __restrict__ bvo,
    unsigned short* __restrict__ Bp3, unsigned short* __restrict__ Bp4,
    unsigned short* __restrict__ Bp5, unsigned short* __restrict__ Bp6)
{
  int idx = blockIdx.x * 256 + threadIdx.x;
  if (idx < 4096) {
    int j = idx >> 6, k = idx & 63;
    float a = 0.f;
    #pragma unroll 4
    for (int l = 0; l < 64; ++l) a = fmaf(Wo[j * 64 + l], Wv[l * 64 + k], a);
    Wvo[idx] = a;
  }
  if (idx < 64) {
    float a = bo[idx];
    for (int l = 0; l < 64; ++l) a = fmaf(Wo[idx * 64 + l], bv[l], a);
    bvo[idx] = a;
  }
  if (idx < 4096) {
    int e8 = idx & 7, ln = (idx >> 3) & 63, t = (idx >> 9) & 1, s = idx >> 10;
    int n = 2 * (ln & 31) + t;
    int k = s * 16 + (ln >> 5) * 8 + e8;
    Bp3[idx] = f2bf(We2[n * 64 + k]);
    Bp4[idx] = f2bf(Wg1[n * 64 + k]);
    Bp5[idx] = f2bf(Wg2[n * 64 + k]);
  }
  if (idx < 2048) {
    int e8 = idx & 7, ln = (idx >> 3) & 63, s = idx >> 9;
    int n = ln & 31;
    int k = s * 16 + (ln >> 5) * 8 + e8;
    Bp6[idx] = (n < 10) ? f2bf(Wnh[n * 64 + k]) : (unsigned short)0;
  }
}

// ---------- prep2: Wall = Wvo @ Wattn (K=128 pack), ball = Wvo@battn + bvo ----------
__global__ __launch_bounds__(256) void k_prep2(
    const float* __restrict__ Wvo,  const float* __restrict__ bvo,
    const float* __restrict__ Wattn, const float* __restrict__ battn,
    unsigned short* __restrict__ Bpf, float* __restrict__ ball)
{
  int idx = blockIdx.x * 256 + threadIdx.x;
  if (idx < 8192) {
    int e8 = idx & 7, ln = (idx >> 3) & 63, t = (idx >> 9) & 1, s = idx >> 10;
    int n = 2 * (ln & 31) + t;
    int k = s * 16 + (ln >> 5) * 8 + e8;
    float a = 0.f;
    #pragma unroll 4
    for (int l = 0; l < 64; ++l)
      a = fmaf(Wvo[n * 64 + l], Wattn[l * 128 + k], a);
    Bpf[idx] = f2bf(a);
  }
  if (idx < 64) {
    float a = bvo[idx];
    for (int l = 0; l < 64; ++l) a = fmaf(Wvo[idx * 64 + l], battn[l], a);
    ball[idx] = a;
  }
}

// ---------- node init: nf16 + agg(f32) ----------
__global__ __launch_bounds__(256) void k_node_init(
    const float* __restrict__ nl, const float* __restrict__ Wproj,
    const float* __restrict__ bproj, unsigned short* __restrict__ nf16,
    float* __restrict__ agg, int N)
{
  int i = blockIdx.x * 256 + threadIdx.x;
  if (i >= N) return;
  float x[10];
  #pragma unroll
  for (int k = 0; k < 10; ++k) x[k] = nl[(size_t)i * 10 + k];
  const size_t ib = (size_t)i * HH;
  #pragma unroll 1
  for (int j8 = 0; j8 < 8; ++j8) {
    float y[8];
    #pragma unroll
    for (int u = 0; u < 8; ++u) {
      int j = j8 * 8 + u;
      float a = bproj[j];
      #pragma unroll
      for (int k = 0; k < 10; ++k) a = fmaf(x[k], Wproj[j * 10 + k], a);
      y[u] = a;
    }
    uintx4 v = { pk2bf(y[0], y[1]), pk2bf(y[2], y[3]),
                 pk2bf(y[4], y[5]), pk2bf(y[6], y[7]) };
    *(uintx4*)(nf16 + ib + j8 * 8) = v;
    float4 a0 = {y[0], y[1], y[2], y[3]};
    float4 a1 = {y[4], y[5], y[6], y[7]};
    *(float4*)(agg + ib + j8 * 8) = a0;
    *(float4*)(agg + ib + j8 * 8 + 4) = a1;
  }
}

// ---------- CSR build ----------
__global__ __launch_bounds__(256) void k_zero(int* __restrict__ p, int n)
{
  int i = blockIdx.x * 256 + threadIdx.x;
  if (i < n) p[i] = 0;
}

__global__ __launch_bounds__(256) void k_deg(
    const int* __restrict__ ei, int* __restrict__ deg, int E)
{
  int e = blockIdx.x * 256 + threadIdx.x;
  if (e >= E) return;
  atomicAdd(&deg[ei[(size_t)E + e]], 1);
}

__global__ __launch_bounds__(256) void k_part(
    const int* __restrict__ deg, int* __restrict__ bpart, int N)
{
  __shared__ int s[256];
  int t = threadIdx.x;
  int i = blockIdx.x * 256 + t;
  s[t] = (i < N) ? deg[i] : 0;
  __syncthreads();
  #pragma unroll
  for (int o = 128; o > 0; o >>= 1) {
    if (t < o) s[t] += s[t + o];
    __syncthreads();
  }
  if (t == 0) bpart[blockIdx.x] = s[0];
}

__global__ __launch_bounds__(256) void k_scanpart(
    const int* __restrict__ bpart, int* __restrict__ bbase,
    int* __restrict__ rowptr_last, int PB)
{
  __shared__ int s[256];
  int t = threadIdx.x;
  int v = (t < PB) ? bpart[t] : 0;
  s[t] = v;
  __syncthreads();
  for (int o = 1; o < 256; o <<= 1) {
    int u = (t >= o) ? s[t - o] : 0;
    __syncthreads();
    s[t] += u;
    __syncthreads();
  }
  if (t < PB) bbase[t] = s[t] - v;
  if (t == 255) *rowptr_last = s[255];
}

__global__ __launch_bounds__(256) void k_rowptr(
    const int* __restrict__ deg, const int* __restrict__ bbase,
    int* __restrict__ rowptr, int* __restrict__ wofs, int N)
{
  __shared__ int s[256];
  int t = threadIdx.x;
  int i = blockIdx.x * 256 + t;
  int v = (i < N) ? deg[i] : 0;
  s[t] = v;
  __syncthreads();
  for (int o = 1; o < 256; o <<= 1) {
    int u = (t >= o) ? s[t - o] : 0;
    __syncthreads();
    s[t] += u;
    __syncthreads();
  }
  if (i < N) {
    int ex = bbase[blockIdx.x] + s[t] - v;
    rowptr[i] = ex;
    wofs[i]   = ex;
  }
}

__global__ __launch_bounds__(256) void k_scatter(
    const int* __restrict__ ei, int* __restrict__ wofs,
    int* __restrict__ eorig, int* __restrict__ srcp, int* __restrict__ dstp,
    int E)
{
  int e = blockIdx.x * 256 + threadIdx.x;
  if (e >= E) return;
  int src = ei[e];
  int dst = ei[(size_t)E + e];
  int pos = atomicAdd(&wofs[dst], 1);
  eorig[pos] = e;
  srcp[pos]  = src;
  dstp[pos]  = dst;
}

// ---------- fused edge + aggregation kernel (known-good structure) ----------
// FIRST: ef0 = We2-MLP(el) computed inline (8 MFMA into same acc; no ef read).
// Always: msg GEMM (16 MFMA, fused Wall), ef' = relu(base + acc + bias) -> store,
// m = relu(nf[src] + ef') -> LDS (column XOR-swizzled); block CSR-run reduction.
// LAST: fused edge head edge_out = ef' @ Weh^T + beh via separate c_lds.
template <bool FIRST, bool LAST>
__global__ __launch_bounds__(256) void k_edge_agg(
    const unsigned short* __restrict__ nf16, unsigned short* __restrict__ ef16,
    const int* __restrict__ srcp, const int* __restrict__ dstp,
    const int* __restrict__ eorig, const int* __restrict__ rowptr,
    const unsigned short* __restrict__ Bpf, const float* __restrict__ ball,
    const unsigned short* __restrict__ Bp3, const float* __restrict__ be2,
    const float* __restrict__ el, const float* __restrict__ We1,
    const float* __restrict__ be1,
    const float* __restrict__ Weh, const float* __restrict__ beh,
    float* __restrict__ edge_out, float* __restrict__ agg, int E)
{
  __shared__ unsigned m_lds[128][32];
  __shared__ __align__(16) unsigned short c_lds[LAST ? 4 * 32 * 64 : 4];
  const int tid    = threadIdx.x;
  const int wave   = tid >> 6;
  const int lane   = tid & 63;
  const int er     = lane & 31;
  const int kh     = lane >> 5;
  const int ebase0 = blockIdx.x * 128;
  const int ebase  = ebase0 + wave * 32;

  int p = ebase + er;
  if (p >= E) p = E - 1;
  const int src = srcp[p];
  const int dst = dstp[p];
  const unsigned short* ns = nf16 + (size_t)src * HH;
  const unsigned short* nd = nf16 + (size_t)dst * HH;

  f32x16 acc0 = {0,0,0,0,0,0,0,0,0,0,0,0,0,0,0,0};
  f32x16 acc1 = {0,0,0,0,0,0,0,0,0,0,0,0,0,0,0,0};

  if (FIRST) {
    // ef0 = relu(el@We1^T+be1) @ We2^T : layer1 VALU -> A-frags -> 8 MFMA
    const int eo = eorig[p];
    const float x0 = el[(size_t)eo * 5 + 0], x1 = el[(size_t)eo * 5 + 1],
                x2 = el[(size_t)eo * 5 + 2], x3 = el[(size_t)eo * 5 + 3],
                x4 = el[(size_t)eo * 5 + 4];
    #pragma unroll
    for (int s = 0; s < 4; ++s) {
      float y[8];
      #pragma unroll
      for (int u = 0; u < 8; ++u) {
        const int k = s * 16 + kh * 8 + u;
        float a = be1[k];
        a = fmaf(x0, We1[k * 5 + 0], a);
        a = fmaf(x1, We1[k * 5 + 1], a);
        a = fmaf(x2, We1[k * 5 + 2], a);
        a = fmaf(x3, We1[k * 5 + 3], a);
        a = fmaf(x4, We1[k * 5 + 4], a);
        y[u] = fmaxf(a, 0.f);
      }
      uintx4 w = { pk2bf(y[0], y[1]), pk2bf(y[2], y[3]),
                   pk2bf(y[4], y[5]), pk2bf(y[6], y[7]) };
      bf16x8 afr = __builtin_bit_cast(bf16x8, w);
      bf16x8 b0 = *(const bf16x8*)(Bp3 + (size_t)((s * 2 + 0) * 64 + lane) * 8);
      bf16x8 b1 = *(const bf16x8*)(Bp3 + (size_t)((s * 2 + 1) * 64 + lane) * 8);
      acc0 = __builtin_amdgcn_mfma_f32_32x32x16_bf16(afr, b0, acc0, 0, 0, 0);
      acc1 = __builtin_amdgcn_mfma_f32_32x32x16_bf16(afr, b1, acc1, 0, 0, 0);
    }
  }

  // msg GEMM: K=128 fused Wall (0-3 from ns, 4-7 from nd)
  #pragma unroll
  for (int s = 0; s < 8; ++s) {
    const unsigned short* ap = (s < 4) ? ns : nd;
    bf16x8 a = *(const bf16x8*)(ap + (s & 3) * 16 + kh * 8);
    bf16x8 b0 = *(const bf16x8*)(Bpf + (size_t)((s * 2 + 0) * 64 + lane) * 8);
    bf16x8 b1 = *(const bf16x8*)(Bpf + (size_t)((s * 2 + 1) * 64 + lane) * 8);
    acc0 = __builtin_amdgcn_mfma_f32_32x32x16_bf16(a, b0, acc0, 0, 0, 0);
    acc1 = __builtin_amdgcn_mfma_f32_32x32x16_bf16(a, b1, acc1, 0, 0, 0);
  }

  // epilogue: ef' = relu(base + acc + bias); store; m = relu(ns+ef') -> LDS
  unsigned* cw32 = (unsigned*)c_lds + wave * 1024;
  const float bt0 = ball[2 * er]     + (FIRST ? be2[2 * er]     : 0.f);
  const float bt1 = ball[2 * er + 1] + (FIRST ? be2[2 * er + 1] : 0.f);
  #pragma unroll
  for (int r = 0; r < 16; ++r) {
    const int m  = (r & 3) + 8 * (r >> 2) + 4 * kh;
    const int eg = ebase + m;
    if (eg < E) {
      float base0 = 0.f, base1 = 0.f;
      if (!FIRST) {
        unsigned old = *((const unsigned*)(ef16 + (size_t)eg * HH) + er);
        base0 = bf2f((unsigned short)(old & 0xffff));
        base1 = bf2f((unsigned short)(old >> 16));
      }
      float x0 = fmaxf(base0 + acc0[r] + bt0, 0.f);
      float x1 = fmaxf(base1 + acc1[r] + bt1, 0.f);
      unsigned q = pk2bf(x0, x1);
      *((unsigned*)(ef16 + (size_t)eg * HH) + er) = q;
      if (LAST)
        cw32[m * 32 + (((er >> 2) ^ (m & 7)) << 2) + (er & 3)] = q;
      // m = relu(nf[src_eg] + ef')
      const int se = srcp[eg];
      unsigned nsv = *((const unsigned*)(nf16 + (size_t)se * HH) + er);
      float m0 = fmaxf(bf2f((unsigned short)(nsv & 0xffff)) + x0, 0.f);
      float m1 = fmaxf(bf2f((unsigned short)(nsv >> 16))    + x1, 0.f);
      const int ls = wave * 32 + m;
      m_lds[ls][er ^ (ls & 31)] = pk2bf(m0, m1);   // column XOR-swizzle
    }
  }

  if (LAST) {
    asm volatile("s_waitcnt lgkmcnt(0)" ::: "memory");
    __builtin_amdgcn_sched_barrier(0);
    if (lane < 32) {
      const int eg = ebase + lane;
      if (eg < E) {
        const unsigned short* cw = c_lds + wave * 2048;
        float a0 = beh[0], a1 = beh[1], a2 = beh[2], a3 = beh[3], a4 = beh[4];
        const int l7 = lane & 7;
        #pragma unroll
        for (int f = 0; f < HH; ++f) {
          float x = bf2f(cw[lane * 64 + (((f >> 3) ^ l7) << 3) + (f & 7)]);
          a0 = fmaf(x, Weh[0 * HH + f], a0);
          a1 = fmaf(x, Weh[1 * HH + f], a1);
          a2 = fmaf(x, Weh[2 * HH + f], a2);
          a3 = fmaf(x, Weh[3 * HH + f], a3);
          a4 = fmaf(x, Weh[4 * HH + f], a4);
        }
        const int eo2 = eorig[eg];
        float* o = edge_out + (size_t)eo2 * 5;
        o[0] = a0; o[1] = a1; o[2] = a2; o[3] = a3; o[4] = a4;
      }
    }
  }

  __syncthreads();

  // block reduction: CSR-contiguous dst runs over this block's 128 slots.
  // interior dst -> plain store nf+sum; boundary dst -> atomicAdd partial
  // (agg pre-initialized to nf by k_node_init / k_node_mlp<false>).
  {
    const int g = tid >> 5;         // 8 groups
    const int l = tid & 31;         // feature pair 2l, 2l+1
    const int lastslot = min(ebase0 + 127, E - 1);
    const int i_lo = dstp[ebase0];
    const int i_hi = dstp[lastslot];
    for (int i = i_lo + g; i <= i_hi; i += 8) {
      const int rb = rowptr[i], re = rowptr[i + 1];
      const int lo = max(rb, ebase0);
      const int hi = min(re, ebase0 + 128);
      float s0 = 0.f, s1 = 0.f;
      for (int pp = lo; pp < hi; ++pp) {
        const int ls = pp - ebase0;
        unsigned v = m_lds[ls][l ^ (ls & 31)];   // swizzled read: conflict-free
        s0 += bf2f((unsigned short)(v & 0xffff));
        s1 += bf2f((unsigned short)(v >> 16));
      }
      const bool interior = (rb >= ebase0) && (re <= ebase0 + 128);
      if (interior) {
        unsigned nv = *((const unsigned*)(nf16 + (size_t)i * HH) + l);
        float2 o = { bf2f((unsigned short)(nv & 0xffff)) + s0,
                     bf2f((unsigned short)(nv >> 16))    + s1 };
        *(float2*)(agg + (size_t)i * HH + 2 * l) = o;
      } else if (hi > lo) {
        atomicAdd(agg + (size_t)i * HH + 2 * l,     s0);
        atomicAdd(agg + (size_t)i * HH + 2 * l + 1, s1);
      }
    }
  }
}

// ---------- node MLP via MFMA (f32 agg input, even/odd pack) ----------
template <bool LAST>
__global__ __launch_bounds__(256) void k_node_mlp(
    const float* __restrict__ agg,
    const unsigned short* __restrict__ Bp4, const float* __restrict__ bg1,
    const unsigned short* __restrict__ Bp5, const float* __restrict__ bg2,
    const unsigned short* __restrict__ Bp6, const float* __restrict__ bnh,
    unsigned short* __restrict__ nf16, float* __restrict__ aggw,
    float* __restrict__ node_out, int N)
{
  __shared__ __align__(16) unsigned short c_lds[4 * 32 * 64];
  const int tid   = threadIdx.x;
  const int wave  = tid >> 6;
  const int lane  = tid & 63;
  const int er    = lane & 31;
  const int kh    = lane >> 5;
  const int nbase = blockIdx.x * 128 + wave * 32;
  if (nbase >= N) return;

  int node = nbase + er;
  if (node >= N) node = N - 1;
  const float* ar = agg + (size_t)node * HH;

  f32x16 acc0 = {0,0,0,0,0,0,0,0,0,0,0,0,0,0,0,0};
  f32x16 acc1 = {0,0,0,0,0,0,0,0,0,0,0,0,0,0,0,0};
  #pragma unroll
  for (int s = 0; s < 4; ++s) {
    float4 fa = *(const float4*)(ar + s * 16 + kh * 8);
    float4 fb = *(const float4*)(ar + s * 16 + kh * 8 + 4);
    uintx4 w = { pk2bf(fa.x, fa.y), pk2bf(fa.z, fa.w),
                 pk2bf(fb.x, fb.y), pk2bf(fb.z, fb.w) };
    bf16x8 a = __builtin_bit_cast(bf16x8, w);
    bf16x8 b0 = *(const bf16x8*)(Bp4 + (size_t)((s * 2 + 0) * 64 + lane) * 8);
    bf16x8 b1 = *(const bf16x8*)(Bp4 + (size_t)((s * 2 + 1) * 64 + lane) * 8);
    acc0 = __builtin_amdgcn_mfma_f32_32x32x16_bf16(a, b0, acc0, 0, 0, 0);
    acc1 = __builtin_amdgcn_mfma_f32_32x32x16_bf16(a, b1, acc1, 0, 0, 0);
  }

  unsigned short* cw = c_lds + wave * 2048;
  unsigned* cw32 = (unsigned*)cw;
  const float bg10 = bg1[2 * er], bg11 = bg1[2 * er + 1];
  #pragma unroll
  for (int r = 0; r < 16; ++r) {
    const int m = (r & 3) + 8 * (r >> 2) + 4 * kh;
    unsigned q = pk2bf(fmaxf(acc0[r] + bg10, 0.f), fmaxf(acc1[r] + bg11, 0.f));
    cw32[m * 32 + (((er >> 2) ^ (m & 7)) << 2) + (er & 3)] = q;
  }
  asm volatile("s_waitcnt lgkmcnt(0)" ::: "memory");
  __builtin_amdgcn_sched_barrier(0);

  f32x16 d0 = {0,0,0,0,0,0,0,0,0,0,0,0,0,0,0,0};
  f32x16 d1 = {0,0,0,0,0,0,0,0,0,0,0,0,0,0,0,0};
  #pragma unroll
  for (int s = 0; s < 4; ++s) {
    const int g = s * 2 + kh;
    bf16x8 a2 = *(const bf16x8*)(cw + er * 64 + ((g ^ (er & 7)) << 3));
    bf16x8 b0 = *(const bf16x8*)(Bp5 + (size_t)((s * 2 + 0) * 64 + lane) * 8);
    bf16x8 b1 = *(const bf16x8*)(Bp5 + (size_t)((s * 2 + 1) * 64 + lane) * 8);
    d0 = __builtin_amdgcn_mfma_f32_32x32x16_bf16(a2, b0, d0, 0, 0, 0);
    d1 = __builtin_amdgcn_mfma_f32_32x32x16_bf16(a2, b1, d1, 0, 0, 0);
  }

  const float bg20 = bg2[2 * er], bg21 = bg2[2 * er + 1];
  if (!LAST) {
    #pragma unroll
    for (int r = 0; r < 16; ++r) {
      const int m  = (r & 3) + 8 * (r >> 2) + 4 * kh;
      const int ng = nbase + m;
      if (ng < N) {
        float v0 = fmaxf(d0[r] + bg20, 0.f);
        float v1 = fmaxf(d1[r] + bg21, 0.f);
        *((unsigned*)(nf16 + (size_t)ng * HH) + er) = pk2bf(v0, v1);
        float2 o = { v0, v1 };
        *(float2*)(aggw + (size_t)ng * HH + 2 * er) = o;
      }
    }
  } else {
    #pragma unroll
    for (int r = 0; r < 16; ++r) {
      const int m = (r & 3) + 8 * (r >> 2) + 4 * kh;
      unsigned q = pk2bf(fmaxf(d0[r] + bg20, 0.f), fmaxf(d1[r] + bg21, 0.f));
      cw32[m * 32 + (((er >> 2) ^ (m & 7)) << 2) + (er & 3)] = q;
    }
    asm volatile("s_waitcnt lgkmcnt(0)" ::: "memory");
    __builtin_amdgcn_sched_barrier(0);

    f32x16 hacc = {0,0,0,0,0,0,0,0,0,0,0,0,0,0,0,0};
    #pragma unroll
    for (int s = 0; s < 4; ++s) {
      const int g = s * 2 + kh;
      bf16x8 a2 = *(const bf16x8*)(cw + er * 64 + ((g ^ (er & 7)) << 3));
      bf16x8 b = *(const bf16x8*)(Bp6 + (size_t)(s * 64 + lane) * 8);
      hacc = __builtin_amdgcn_mfma_f32_32x32x16_bf16(a2, b, hacc, 0, 0, 0);
    }
    if (er < 10) {
      const float bn = bnh[er];
      #pragma unroll
      for (int r = 0; r < 16; ++r) {
        const int m  = (r & 3) + 8 * (r >> 2) + 4 * kh;
        const int ng = nbase + m;
        if (ng < N) node_out[(size_t)ng * 10 + er] = hacc[r] + bn;
      }
    }
  }
}

extern "C" void kernel_launch(void* const* d_in, const int* in_sizes, int n_in,
                              void* d_out, int out_size, void* d_ws, size_t ws_size,
                              hipStream_t stream)
{
  const float* node_logits = (const float*)d_in[0];
  const float* edge_logits = (const float*)d_in[1];
  const int*   ei          = (const int*)d_in[2];
  const float* Wproj = (const float*)d_in[3];
  const float* bproj = (const float*)d_in[4];
  const float* We1   = (const float*)d_in[5];
  const float* be1   = (const float*)d_in[6];
  const float* We2   = (const float*)d_in[7];
  const float* be2   = (const float*)d_in[8];
  const float* Wg1   = (const float*)d_in[9];
  const float* bg1   = (const float*)d_in[10];
  const float* Wg2   = (const float*)d_in[11];
  const float* bg2   = (const float*)d_in[12];
  const float* Wv    = (const float*)d_in[13];
  const float* bv    = (const float*)d_in[14];
  const float* Wo    = (const float*)d_in[15];
  const float* bo    = (const float*)d_in[16];
  const float* Wattn = (const float*)d_in[17];
  const float* battn = (const float*)d_in[18];
  const float* Wnh   = (const float*)d_in[19];
  const float* bnh   = (const float*)d_in[20];
  const float* Weh   = (const float*)d_in[21];
  const float* beh   = (const float*)d_in[22];

  const int N = in_sizes[0] / 10;
  const int E = in_sizes[1] / 5;

  float* ws = (float*)d_ws;
  size_t off = 0;
  unsigned short* nf16 = (unsigned short*)(ws + off); off += (size_t)N * (HH / 2);
  unsigned short* ef16 = (unsigned short*)(ws + off); off += (size_t)E * (HH / 2);
  float* agg  = ws + off; off += (size_t)N * HH;
  float* Wvo  = ws + off; off += 64 * 64;
  float* bvo  = ws + off; off += 64;
  float* ball = ws + off; off += 64;
  unsigned short* Bpf = (unsigned short*)(ws + off); off += 4096;
  unsigned short* Bp3 = (unsigned short*)(ws + off); off += 2048;
  unsigned short* Bp4 = (unsigned short*)(ws + off); off += 2048;
  unsigned short* Bp5 = (unsigned short*)(ws + off); off += 2048;
  unsigned short* Bp6 = (unsigned short*)(ws + off); off += 1024;
  int* deg    = (int*)(ws + off); off += N;
  int* rowptr = (int*)(ws + off); off += N + 1;
  int* wofs   = (int*)(ws + off); off += N;
  int* eorig  = (int*)(ws + off); off += E;
  int* srcp   = (int*)(ws + off); off += E;
  int* dstp   = (int*)(ws + off); off += E;
  int* bpart  = (int*)(ws + off); off += 256;
  int* bbase  = (int*)(ws + off); off += 256;

  float* node_out = (float*)d_out;
  float* edge_out = node_out + (size_t)N * 10;

  const int nb_n    = (N + 255) / 256;
  const int nb_e    = (E + 255) / 256;
  const int nb_e128 = (E + 127) / 128;
  const int nb_n128 = (N + 127) / 128;
  const int PB      = (N + 255) / 256;

  k_prep<<<32, 256, 0, stream>>>(Wg1, Wg2, Wnh, Wo, Wv, bv, bo, We2,
                                 Wvo, bvo, Bp3, Bp4, Bp5, Bp6);
  k_prep2<<<32, 256, 0, stream>>>(Wvo, bvo, Wattn, battn, Bpf, ball);
  k_zero<<<nb_n, 256, 0, stream>>>(deg, N);
  k_node_init<<<nb_n, 256, 0, stream>>>(node_logits, Wproj, bproj, nf16, agg, N);
  k_deg<<<nb_e, 256, 0, stream>>>(ei, deg, E);
  k_part<<<PB, 256, 0, stream>>>(deg, bpart, N);
  k_scanpart<<<1, 256, 0, stream>>>(bpart, bbase, rowptr + N, PB);
  k_rowptr<<<PB, 256, 0, stream>>>(deg, bbase, rowptr, wofs, N);
  k_scatter<<<nb_e, 256, 0, stream>>>(ei, wofs, eorig, srcp, dstp, E);

  // iteration 1 (edge-init fused; agg pre-initialized by k_node_init)
  k_edge_agg<true, false><<<nb_e128, 256, 0, stream>>>(
      nf16, ef16, srcp, dstp, eorig, rowptr, Bpf, ball, Bp3, be2,
      edge_logits, We1, be1, Weh, beh, edge_out, agg, E);
  k_node_mlp<false><<<nb_n128, 256, 0, stream>>>(agg, Bp4, bg1, Bp5, bg2,
                                                 Bp6, bnh, nf16, agg, node_out, N);
  // iteration 2 (agg re-initialized by k_node_mlp<false>)
  k_edge_agg<false, true><<<nb_e128, 256, 0, stream>>>(
      nf16, ef16, srcp, dstp, eorig, rowptr, Bpf, ball, Bp3, be2,
      edge_logits, We1, be1, Weh, beh, edge_out, agg, E);
  k_node_mlp<true><<<nb_n128, 256, 0, stream>>>(agg, Bp4, bg1, Bp5, bg2,
                                                Bp6, bnh, nf16, agg, node_out, N);
}

// Round 15
// 398.788 us; speedup vs baseline: 1.0063x; 1.0063x over previous
//
#include <hip/hip_runtime.h>

#define HH 64

typedef __attribute__((ext_vector_type(8))) short bf16x8;
typedef __attribute__((ext_vector_type(16))) float f32x16;
typedef __attribute__((ext_vector_type(4))) unsigned uintx4;

__device__ __forceinline__ unsigned short f2bf(float f) {
  unsigned u = __builtin_bit_cast(unsigned, f);
  return (unsigned short)((u + 0x7FFFu + ((u >> 16) & 1u)) >> 16);
}
__device__ __forceinline__ float bf2f(unsigned short h) {
  unsigned u = ((unsigned)h) << 16;
  return __builtin_bit_cast(float, u);
}
__device__ __forceinline__ unsigned pk2bf(float lo, float hi) {
  unsigned r;
  asm("v_cvt_pk_bf16_f32 %0, %1, %2" : "=v"(r) : "v"(lo), "v"(hi));
  return r;
}

// ---------- prep: Wvo = Wo@Wv, bvo = Wo@bv + bo, B-packs ----------
// EVEN/ODD pack: n = 2*(ln&31) + t ; k = s*16 + (ln>>5)*8 + e8
__global__ __launch_bounds__(256) void k_prep(
    const float* __restrict__ Wg1, const float* __restrict__ Wg2,
    const float* __restrict__ Wnh, const float* __restrict__ Wo,
    const float* __restrict__ Wv,  const float* __restrict__ bv,
    const float* __restrict__ bo,  const float* __restrict__ We2,
    float* __restrict__ Wvo, float* __restrict__ bvo,
    unsigned short* __restrict__ Bp3, unsigned short* __restrict__ Bp4,
    unsigned short* __restrict__ Bp5, unsigned short* __restrict__ Bp6)
{
  int idx = blockIdx.x * 256 + threadIdx.x;
  if (idx < 4096) {
    int j = idx >> 6, k = idx & 63;
    float a = 0.f;
    #pragma unroll 4
    for (int l = 0; l < 64; ++l) a = fmaf(Wo[j * 64 + l], Wv[l * 64 + k], a);
    Wvo[idx] = a;
  }
  if (idx < 64) {
    float a = bo[idx];
    for (int l = 0; l < 64; ++l) a = fmaf(Wo[idx * 64 + l], bv[l], a);
    bvo[idx] = a;
  }
  if (idx < 4096) {
    int e8 = idx & 7, ln = (idx >> 3) & 63, t = (idx >> 9) & 1, s = idx >> 10;
    int n = 2 * (ln & 31) + t;
    int k = s * 16 + (ln >> 5) * 8 + e8;
    Bp3[idx] = f2bf(We2[n * 64 + k]);
    Bp4[idx] = f2bf(Wg1[n * 64 + k]);
    Bp5[idx] = f2bf(Wg2[n * 64 + k]);
  }
  if (idx < 2048) {
    int e8 = idx & 7, ln = (idx >> 3) & 63, s = idx >> 9;
    int n = ln & 31;
    int k = s * 16 + (ln >> 5) * 8 + e8;
    Bp6[idx] = (n < 10) ? f2bf(Wnh[n * 64 + k]) : (unsigned short)0;
  }
}

// ---------- prep2: Wall = Wvo @ Wattn (K=128 pack), ball = Wvo@battn + bvo ----------
__global__ __launch_bounds__(256) void k_prep2(
    const float* __restrict__ Wvo,  const float* __restrict__ bvo,
    const float* __restrict__ Wattn, const float* __restrict__ battn,
    unsigned short* __restrict__ Bpf, float* __restrict__ ball)
{
  int idx = blockIdx.x * 256 + threadIdx.x;
  if (idx < 8192) {
    int e8 = idx & 7, ln = (idx >> 3) & 63, t = (idx >> 9) & 1, s = idx >> 10;
    int n = 2 * (ln & 31) + t;
    int k = s * 16 + (ln >> 5) * 8 + e8;
    float a = 0.f;
    #pragma unroll 4
    for (int l = 0; l < 64; ++l)
      a = fmaf(Wvo[n * 64 + l], Wattn[l * 128 + k], a);
    Bpf[idx] = f2bf(a);
  }
  if (idx < 64) {
    float a = bvo[idx];
    for (int l = 0; l < 64; ++l) a = fmaf(Wvo[idx * 64 + l], battn[l], a);
    ball[idx] = a;
  }
}

// ---------- node init: nf16 + agg(f32) ----------
__global__ __launch_bounds__(256) void k_node_init(
    const float* __restrict__ nl, const float* __restrict__ Wproj,
    const float* __restrict__ bproj, unsigned short* __restrict__ nf16,
    float* __restrict__ agg, int N)
{
  int i = blockIdx.x * 256 + threadIdx.x;
  if (i >= N) return;
  float x[10];
  #pragma unroll
  for (int k = 0; k < 10; ++k) x[k] = nl[(size_t)i * 10 + k];
  const size_t ib = (size_t)i * HH;
  #pragma unroll 1
  for (int j8 = 0; j8 < 8; ++j8) {
    float y[8];
    #pragma unroll
    for (int u = 0; u < 8; ++u) {
      int j = j8 * 8 + u;
      float a = bproj[j];
      #pragma unroll
      for (int k = 0; k < 10; ++k) a = fmaf(x[k], Wproj[j * 10 + k], a);
      y[u] = a;
    }
    uintx4 v = { pk2bf(y[0], y[1]), pk2bf(y[2], y[3]),
                 pk2bf(y[4], y[5]), pk2bf(y[6], y[7]) };
    *(uintx4*)(nf16 + ib + j8 * 8) = v;
    float4 a0 = {y[0], y[1], y[2], y[3]};
    float4 a1 = {y[4], y[5], y[6], y[7]};
    *(float4*)(agg + ib + j8 * 8) = a0;
    *(float4*)(agg + ib + j8 * 8 + 4) = a1;
  }
}

// ---------- CSR build ----------
__global__ __launch_bounds__(256) void k_zero(int* __restrict__ p, int n)
{
  int i = blockIdx.x * 256 + threadIdx.x;
  if (i < n) p[i] = 0;
}

__global__ __launch_bounds__(256) void k_deg(
    const int* __restrict__ ei, int* __restrict__ deg, int E)
{
  int e = blockIdx.x * 256 + threadIdx.x;
  if (e >= E) return;
  atomicAdd(&deg[ei[(size_t)E + e]], 1);
}

__global__ __launch_bounds__(256) void k_part(
    const int* __restrict__ deg, int* __restrict__ bpart, int N)
{
  __shared__ int s[256];
  int t = threadIdx.x;
  int i = blockIdx.x * 256 + t;
  s[t] = (i < N) ? deg[i] : 0;
  __syncthreads();
  #pragma unroll
  for (int o = 128; o > 0; o >>= 1) {
    if (t < o) s[t] += s[t + o];
    __syncthreads();
  }
  if (t == 0) bpart[blockIdx.x] = s[0];
}

__global__ __launch_bounds__(256) void k_scanpart(
    const int* __restrict__ bpart, int* __restrict__ bbase,
    int* __restrict__ rowptr_last, int PB)
{
  __shared__ int s[256];
  int t = threadIdx.x;
  int v = (t < PB) ? bpart[t] : 0;
  s[t] = v;
  __syncthreads();
  for (int o = 1; o < 256; o <<= 1) {
    int u = (t >= o) ? s[t - o] : 0;
    __syncthreads();
    s[t] += u;
    __syncthreads();
  }
  if (t < PB) bbase[t] = s[t] - v;
  if (t == 255) *rowptr_last = s[255];
}

__global__ __launch_bounds__(256) void k_rowptr(
    const int* __restrict__ deg, const int* __restrict__ bbase,
    int* __restrict__ rowptr, int* __restrict__ wofs, int N)
{
  __shared__ int s[256];
  int t = threadIdx.x;
  int i = blockIdx.x * 256 + t;
  int v = (i < N) ? deg[i] : 0;
  s[t] = v;
  __syncthreads();
  for (int o = 1; o < 256; o <<= 1) {
    int u = (t >= o) ? s[t - o] : 0;
    __syncthreads();
    s[t] += u;
    __syncthreads();
  }
  if (i < N) {
    int ex = bbase[blockIdx.x] + s[t] - v;
    rowptr[i] = ex;
    wofs[i]   = ex;
  }
}

// scatter into CSR slots; also materialize el in slot order (el5) so the
// edge kernel's FIRST path reads coalesced instead of a random gather.
__global__ __launch_bounds__(256) void k_scatter(
    const int* __restrict__ ei, int* __restrict__ wofs,
    const float* __restrict__ el,
    int* __restrict__ eorig, int* __restrict__ srcp, int* __restrict__ dstp,
    float* __restrict__ el5, int E)
{
  int e = blockIdx.x * 256 + threadIdx.x;
  if (e >= E) return;
  int src = ei[e];
  int dst = ei[(size_t)E + e];
  float x0 = el[(size_t)e * 5 + 0], x1 = el[(size_t)e * 5 + 1],
        x2 = el[(size_t)e * 5 + 2], x3 = el[(size_t)e * 5 + 3],
        x4 = el[(size_t)e * 5 + 4];
  int pos = atomicAdd(&wofs[dst], 1);
  eorig[pos] = e;
  srcp[pos]  = src;
  dstp[pos]  = dst;
  float* o = el5 + (size_t)pos * 5;
  o[0] = x0; o[1] = x1; o[2] = x2; o[3] = x3; o[4] = x4;
}

// ---------- fused edge + aggregation kernel (known-good structure) ----------
// FIRST: ef0 = We2-MLP(el5) computed inline (8 MFMA into same acc; no ef read).
// Always: msg GEMM (16 MFMA, fused Wall) under setprio(1), ef' RMW -> store,
// m = relu(nf[src] + ef') -> LDS (column XOR-swizzled); block CSR-run reduction.
// LAST: fused edge head edge_out = ef' @ Weh^T + beh via separate c_lds.
template <bool FIRST, bool LAST>
__global__ __launch_bounds__(256) void k_edge_agg(
    const unsigned short* __restrict__ nf16, unsigned short* __restrict__ ef16,
    const int* __restrict__ srcp, const int* __restrict__ dstp,
    const int* __restrict__ eorig, const int* __restrict__ rowptr,
    const unsigned short* __restrict__ Bpf, const float* __restrict__ ball,
    const unsigned short* __restrict__ Bp3, const float* __restrict__ be2,
    const float* __restrict__ el5, const float* __restrict__ We1,
    const float* __restrict__ be1,
    const float* __restrict__ Weh, const float* __restrict__ beh,
    float* __restrict__ edge_out, float* __restrict__ agg, int E)
{
  __shared__ unsigned m_lds[128][32];
  __shared__ __align__(16) unsigned short c_lds[LAST ? 4 * 32 * 64 : 4];
  const int tid    = threadIdx.x;
  const int wave   = tid >> 6;
  const int lane   = tid & 63;
  const int er     = lane & 31;
  const int kh     = lane >> 5;
  const int ebase0 = blockIdx.x * 128;
  const int ebase  = ebase0 + wave * 32;

  int p = ebase + er;
  if (p >= E) p = E - 1;
  const int src = srcp[p];
  const int dst = dstp[p];
  const unsigned short* ns = nf16 + (size_t)src * HH;
  const unsigned short* nd = nf16 + (size_t)dst * HH;

  // hoisted reduction indices: independent loads, overlap with the GEMM
  const int lastslot = min(ebase0 + 127, E - 1);
  const int i_lo = dstp[ebase0];
  const int i_hi = dstp[lastslot];

  f32x16 acc0 = {0,0,0,0,0,0,0,0,0,0,0,0,0,0,0,0};
  f32x16 acc1 = {0,0,0,0,0,0,0,0,0,0,0,0,0,0,0,0};

  __builtin_amdgcn_s_setprio(1);

  if (FIRST) {
    // ef0 = relu(el5@We1^T+be1) @ We2^T : layer1 VALU -> A-frags -> 8 MFMA
    const float x0 = el5[(size_t)p * 5 + 0], x1 = el5[(size_t)p * 5 + 1],
                x2 = el5[(size_t)p * 5 + 2], x3 = el5[(size_t)p * 5 + 3],
                x4 = el5[(size_t)p * 5 + 4];
    #pragma unroll
    for (int s = 0; s < 4; ++s) {
      float y[8];
      #pragma unroll
      for (int u = 0; u < 8; ++u) {
        const int k = s * 16 + kh * 8 + u;
        float a = be1[k];
        a = fmaf(x0, We1[k * 5 + 0], a);
        a = fmaf(x1, We1[k * 5 + 1], a);
        a = fmaf(x2, We1[k * 5 + 2], a);
        a = fmaf(x3, We1[k * 5 + 3], a);
        a = fmaf(x4, We1[k * 5 + 4], a);
        y[u] = fmaxf(a, 0.f);
      }
      uintx4 w = { pk2bf(y[0], y[1]), pk2bf(y[2], y[3]),
                   pk2bf(y[4], y[5]), pk2bf(y[6], y[7]) };
      bf16x8 afr = __builtin_bit_cast(bf16x8, w);
      bf16x8 b0 = *(const bf16x8*)(Bp3 + (size_t)((s * 2 + 0) * 64 + lane) * 8);
      bf16x8 b1 = *(const bf16x8*)(Bp3 + (size_t)((s * 2 + 1) * 64 + lane) * 8);
      acc0 = __builtin_amdgcn_mfma_f32_32x32x16_bf16(afr, b0, acc0, 0, 0, 0);
      acc1 = __builtin_amdgcn_mfma_f32_32x32x16_bf16(afr, b1, acc1, 0, 0, 0);
    }
  }

  // msg GEMM: K=128 fused Wall (0-3 from ns, 4-7 from nd)
  #pragma unroll
  for (int s = 0; s < 8; ++s) {
    const unsigned short* ap = (s < 4) ? ns : nd;
    bf16x8 a = *(const bf16x8*)(ap + (s & 3) * 16 + kh * 8);
    bf16x8 b0 = *(const bf16x8*)(Bpf + (size_t)((s * 2 + 0) * 64 + lane) * 8);
    bf16x8 b1 = *(const bf16x8*)(Bpf + (size_t)((s * 2 + 1) * 64 + lane) * 8);
    acc0 = __builtin_amdgcn_mfma_f32_32x32x16_bf16(a, b0, acc0, 0, 0, 0);
    acc1 = __builtin_amdgcn_mfma_f32_32x32x16_bf16(a, b1, acc1, 0, 0, 0);
  }

  __builtin_amdgcn_s_setprio(0);

  // epilogue: ef' = relu(base + acc + bias); store; m = relu(ns+ef') -> LDS
  unsigned* cw32 = (unsigned*)c_lds + wave * 1024;
  const float bt0 = ball[2 * er]     + (FIRST ? be2[2 * er]     : 0.f);
  const float bt1 = ball[2 * er + 1] + (FIRST ? be2[2 * er + 1] : 0.f);
  #pragma unroll
  for (int r = 0; r < 16; ++r) {
    const int m  = (r & 3) + 8 * (r >> 2) + 4 * kh;
    const int eg = ebase + m;
    if (eg < E) {
      float base0 = 0.f, base1 = 0.f;
      if (!FIRST) {
        unsigned old = *((const unsigned*)(ef16 + (size_t)eg * HH) + er);
        base0 = bf2f((unsigned short)(old & 0xffff));
        base1 = bf2f((unsigned short)(old >> 16));
      }
      float x0 = fmaxf(base0 + acc0[r] + bt0, 0.f);
      float x1 = fmaxf(base1 + acc1[r] + bt1, 0.f);
      unsigned q = pk2bf(x0, x1);
      *((unsigned*)(ef16 + (size_t)eg * HH) + er) = q;
      if (LAST)
        cw32[m * 32 + (((er >> 2) ^ (m & 7)) << 2) + (er & 3)] = q;
      // m = relu(nf[src_eg] + ef')
      const int se = srcp[eg];
      unsigned nsv = *((const unsigned*)(nf16 + (size_t)se * HH) + er);
      float m0 = fmaxf(bf2f((unsigned short)(nsv & 0xffff)) + x0, 0.f);
      float m1 = fmaxf(bf2f((unsigned short)(nsv >> 16))    + x1, 0.f);
      const int ls = wave * 32 + m;
      m_lds[ls][er ^ (ls & 31)] = pk2bf(m0, m1);   // column XOR-swizzle
    }
  }

  if (LAST) {
    asm volatile("s_waitcnt lgkmcnt(0)" ::: "memory");
    __builtin_amdgcn_sched_barrier(0);
    if (lane < 32) {
      const int eg = ebase + lane;
      if (eg < E) {
        const unsigned short* cw = c_lds + wave * 2048;
        float a0 = beh[0], a1 = beh[1], a2 = beh[2], a3 = beh[3], a4 = beh[4];
        const int l7 = lane & 7;
        #pragma unroll
        for (int f = 0; f < HH; ++f) {
          float x = bf2f(cw[lane * 64 + (((f >> 3) ^ l7) << 3) + (f & 7)]);
          a0 = fmaf(x, Weh[0 * HH + f], a0);
          a1 = fmaf(x, Weh[1 * HH + f], a1);
          a2 = fmaf(x, Weh[2 * HH + f], a2);
          a3 = fmaf(x, Weh[3 * HH + f], a3);
          a4 = fmaf(x, Weh[4 * HH + f], a4);
        }
        const int eo2 = eorig[eg];
        float* o = edge_out + (size_t)eo2 * 5;
        o[0] = a0; o[1] = a1; o[2] = a2; o[3] = a3; o[4] = a4;
      }
    }
  }

  __syncthreads();

  // block reduction: CSR-contiguous dst runs over this block's 128 slots.
  // interior dst -> plain store nf+sum; boundary dst -> atomicAdd partial
  // (agg pre-initialized to nf by k_node_init / k_node_mlp<false>).
  {
    const int g = tid >> 5;         // 8 groups
    const int l = tid & 31;         // feature pair 2l, 2l+1
    for (int i = i_lo + g; i <= i_hi; i += 8) {
      const int rb = rowptr[i], re = rowptr[i + 1];
      const int lo = max(rb, ebase0);
      const int hi = min(re, ebase0 + 128);
      float s0 = 0.f, s1 = 0.f;
      for (int pp = lo; pp < hi; ++pp) {
        const int ls = pp - ebase0;
        unsigned v = m_lds[ls][l ^ (ls & 31)];   // swizzled read: conflict-free
        s0 += bf2f((unsigned short)(v & 0xffff));
        s1 += bf2f((unsigned short)(v >> 16));
      }
      const bool interior = (rb >= ebase0) && (re <= ebase0 + 128);
      if (interior) {
        unsigned nv = *((const unsigned*)(nf16 + (size_t)i * HH) + l);
        float2 o = { bf2f((unsigned short)(nv & 0xffff)) + s0,
                     bf2f((unsigned short)(nv >> 16))    + s1 };
        *(float2*)(agg + (size_t)i * HH + 2 * l) = o;
      } else if (hi > lo) {
        atomicAdd(agg + (size_t)i * HH + 2 * l,     s0);
        atomicAdd(agg + (size_t)i * HH + 2 * l + 1, s1);
      }
    }
  }
}

// ---------- node MLP via MFMA (f32 agg input, even/odd pack) ----------
template <bool LAST>
__global__ __launch_bounds__(256) void k_node_mlp(
    const float* __restrict__ agg,
    const unsigned short* __restrict__ Bp4, const float* __restrict__ bg1,
    const unsigned short* __restrict__ Bp5, const float* __restrict__ bg2,
    const unsigned short* __restrict__ Bp6, const float* __restrict__ bnh,
    unsigned short* __restrict__ nf16, float* __restrict__ aggw,
    float* __restrict__ node_out, int N)
{
  __shared__ __align__(16) unsigned short c_lds[4 * 32 * 64];
  const int tid   = threadIdx.x;
  const int wave  = tid >> 6;
  const int lane  = tid & 63;
  const int er    = lane & 31;
  const int kh    = lane >> 5;
  const int nbase = blockIdx.x * 128 + wave * 32;
  if (nbase >= N) return;

  int node = nbase + er;
  if (node >= N) node = N - 1;
  const float* ar = agg + (size_t)node * HH;

  f32x16 acc0 = {0,0,0,0,0,0,0,0,0,0,0,0,0,0,0,0};
  f32x16 acc1 = {0,0,0,0,0,0,0,0,0,0,0,0,0,0,0,0};
  #pragma unroll
  for (int s = 0; s < 4; ++s) {
    float4 fa = *(const float4*)(ar + s * 16 + kh * 8);
    float4 fb = *(const float4*)(ar + s * 16 + kh * 8 + 4);
    uintx4 w = { pk2bf(fa.x, fa.y), pk2bf(fa.z, fa.w),
                 pk2bf(fb.x, fb.y), pk2bf(fb.z, fb.w) };
    bf16x8 a = __builtin_bit_cast(bf16x8, w);
    bf16x8 b0 = *(const bf16x8*)(Bp4 + (size_t)((s * 2 + 0) * 64 + lane) * 8);
    bf16x8 b1 = *(const bf16x8*)(Bp4 + (size_t)((s * 2 + 1) * 64 + lane) * 8);
    acc0 = __builtin_amdgcn_mfma_f32_32x32x16_bf16(a, b0, acc0, 0, 0, 0);
    acc1 = __builtin_amdgcn_mfma_f32_32x32x16_bf16(a, b1, acc1, 0, 0, 0);
  }

  unsigned short* cw = c_lds + wave * 2048;
  unsigned* cw32 = (unsigned*)cw;
  const float bg10 = bg1[2 * er], bg11 = bg1[2 * er + 1];
  #pragma unroll
  for (int r = 0; r < 16; ++r) {
    const int m = (r & 3) + 8 * (r >> 2) + 4 * kh;
    unsigned q = pk2bf(fmaxf(acc0[r] + bg10, 0.f), fmaxf(acc1[r] + bg11, 0.f));
    cw32[m * 32 + (((er >> 2) ^ (m & 7)) << 2) + (er & 3)] = q;
  }
  asm volatile("s_waitcnt lgkmcnt(0)" ::: "memory");
  __builtin_amdgcn_sched_barrier(0);

  f32x16 d0 = {0,0,0,0,0,0,0,0,0,0,0,0,0,0,0,0};
  f32x16 d1 = {0,0,0,0,0,0,0,0,0,0,0,0,0,0,0,0};
  #pragma unroll
  for (int s = 0; s < 4; ++s) {
    const int g = s * 2 + kh;
    bf16x8 a2 = *(const bf16x8*)(cw + er * 64 + ((g ^ (er & 7)) << 3));
    bf16x8 b0 = *(const bf16x8*)(Bp5 + (size_t)((s * 2 + 0) * 64 + lane) * 8);
    bf16x8 b1 = *(const bf16x8*)(Bp5 + (size_t)((s * 2 + 1) * 64 + lane) * 8);
    d0 = __builtin_amdgcn_mfma_f32_32x32x16_bf16(a2, b0, d0, 0, 0, 0);
    d1 = __builtin_amdgcn_mfma_f32_32x32x16_bf16(a2, b1, d1, 0, 0, 0);
  }

  const float bg20 = bg2[2 * er], bg21 = bg2[2 * er + 1];
  if (!LAST) {
    #pragma unroll
    for (int r = 0; r < 16; ++r) {
      const int m  = (r & 3) + 8 * (r >> 2) + 4 * kh;
      const int ng = nbase + m;
      if (ng < N) {
        float v0 = fmaxf(d0[r] + bg20, 0.f);
        float v1 = fmaxf(d1[r] + bg21, 0.f);
        *((unsigned*)(nf16 + (size_t)ng * HH) + er) = pk2bf(v0, v1);
        float2 o = { v0, v1 };
        *(float2*)(aggw + (size_t)ng * HH + 2 * er) = o;
      }
    }
  } else {
    #pragma unroll
    for (int r = 0; r < 16; ++r) {
      const int m = (r & 3) + 8 * (r >> 2) + 4 * kh;
      unsigned q = pk2bf(fmaxf(d0[r] + bg20, 0.f), fmaxf(d1[r] + bg21, 0.f));
      cw32[m * 32 + (((er >> 2) ^ (m & 7)) << 2) + (er & 3)] = q;
    }
    asm volatile("s_waitcnt lgkmcnt(0)" ::: "memory");
    __builtin_amdgcn_sched_barrier(0);

    f32x16 hacc = {0,0,0,0,0,0,0,0,0,0,0,0,0,0,0,0};
    #pragma unroll
    for (int s = 0; s < 4; ++s) {
      const int g = s * 2 + kh;
      bf16x8 a2 = *(const bf16x8*)(cw + er * 64 + ((g ^ (er & 7)) << 3));
      bf16x8 b = *(const bf16x8*)(Bp6 + (size_t)(s * 64 + lane) * 8);
      hacc = __builtin_amdgcn_mfma_f32_32x32x16_bf16(a2, b, hacc, 0, 0, 0);
    }
    if (er < 10) {
      const float bn = bnh[er];
      #pragma unroll
      for (int r = 0; r < 16; ++r) {
        const int m  = (r & 3) + 8 * (r >> 2) + 4 * kh;
        const int ng = nbase + m;
        if (ng < N) node_out[(size_t)ng * 10 + er] = hacc[r] + bn;
      }
    }
  }
}

extern "C" void kernel_launch(void* const* d_in, const int* in_sizes, int n_in,
                              void* d_out, int out_size, void* d_ws, size_t ws_size,
                              hipStream_t stream)
{
  const float* node_logits = (const float*)d_in[0];
  const float* edge_logits = (const float*)d_in[1];
  const int*   ei          = (const int*)d_in[2];
  const float* Wproj = (const float*)d_in[3];
  const float* bproj = (const float*)d_in[4];
  const float* We1   = (const float*)d_in[5];
  const float* be1   = (const float*)d_in[6];
  const float* We2   = (const float*)d_in[7];
  const float* be2   = (const float*)d_in[8];
  const float* Wg1   = (const float*)d_in[9];
  const float* bg1   = (const float*)d_in[10];
  const float* Wg2   = (const float*)d_in[11];
  const float* bg2   = (const float*)d_in[12];
  const float* Wv    = (const float*)d_in[13];
  const float* bv    = (const float*)d_in[14];
  const float* Wo    = (const float*)d_in[15];
  const float* bo    = (const float*)d_in[16];
  const float* Wattn = (const float*)d_in[17];
  const float* battn = (const float*)d_in[18];
  const float* Wnh   = (const float*)d_in[19];
  const float* bnh   = (const float*)d_in[20];
  const float* Weh   = (const float*)d_in[21];
  const float* beh   = (const float*)d_in[22];

  const int N = in_sizes[0] / 10;
  const int E = in_sizes[1] / 5;

  float* ws = (float*)d_ws;
  size_t off = 0;
  unsigned short* nf16 = (unsigned short*)(ws + off); off += (size_t)N * (HH / 2);
  unsigned short* ef16 = (unsigned short*)(ws + off); off += (size_t)E * (HH / 2);
  float* agg  = ws + off; off += (size_t)N * HH;
  float* Wvo  = ws + off; off += 64 * 64;
  float* bvo  = ws + off; off += 64;
  float* ball = ws + off; off += 64;
  unsigned short* Bpf = (unsigned short*)(ws + off); off += 4096;
  unsigned short* Bp3 = (unsigned short*)(ws + off); off += 2048;
  unsigned short* Bp4 = (unsigned short*)(ws + off); off += 2048;
  unsigned short* Bp5 = (unsigned short*)(ws + off); off += 2048;
  unsigned short* Bp6 = (unsigned short*)(ws + off); off += 1024;
  int* deg    = (int*)(ws + off); off += N;
  int* rowptr = (int*)(ws + off); off += N + 1;
  int* wofs   = (int*)(ws + off); off += N;
  int* eorig  = (int*)(ws + off); off += E;
  int* srcp   = (int*)(ws + off); off += E;
  int* dstp   = (int*)(ws + off); off += E;
  float* el5  = ws + off; off += (size_t)E * 5;
  int* bpart  = (int*)(ws + off); off += 256;
  int* bbase  = (int*)(ws + off); off += 256;

  float* node_out = (float*)d_out;
  float* edge_out = node_out + (size_t)N * 10;

  const int nb_n    = (N + 255) / 256;
  const int nb_e    = (E + 255) / 256;
  const int nb_e128 = (E + 127) / 128;
  const int nb_n128 = (N + 127) / 128;
  const int PB      = (N + 255) / 256;

  k_prep<<<32, 256, 0, stream>>>(Wg1, Wg2, Wnh, Wo, Wv, bv, bo, We2,
                                 Wvo, bvo, Bp3, Bp4, Bp5, Bp6);
  k_prep2<<<32, 256, 0, stream>>>(Wvo, bvo, Wattn, battn, Bpf, ball);
  k_zero<<<nb_n, 256, 0, stream>>>(deg, N);
  k_node_init<<<nb_n, 256, 0, stream>>>(node_logits, Wproj, bproj, nf16, agg, N);
  k_deg<<<nb_e, 256, 0, stream>>>(ei, deg, E);
  k_part<<<PB, 256, 0, stream>>>(deg, bpart, N);
  k_scanpart<<<1, 256, 0, stream>>>(bpart, bbase, rowptr + N, PB);
  k_rowptr<<<PB, 256, 0, stream>>>(deg, bbase, rowptr, wofs, N);
  k_scatter<<<nb_e, 256, 0, stream>>>(ei, wofs, edge_logits, eorig, srcp, dstp,
                                      el5, E);

  // iteration 1 (edge-init fused; agg pre-initialized by k_node_init)
  k_edge_agg<true, false><<<nb_e128, 256, 0, stream>>>(
      nf16, ef16, srcp, dstp, eorig, rowptr, Bpf, ball, Bp3, be2,
      el5, We1, be1, Weh, beh, edge_out, agg, E);
  k_node_mlp<false><<<nb_n128, 256, 0, stream>>>(agg, Bp4, bg1, Bp5, bg2,
                                                 Bp6, bnh, nf16, agg, node_out, N);
  // iteration 2 (agg re-initialized by k_node_mlp<false>)
  k_edge_agg<false, true><<<nb_e128, 256, 0, stream>>>(
      nf16, ef16, srcp, dstp, eorig, rowptr, Bpf, ball, Bp3, be2,
      el5, We1, be1, Weh, beh, edge_out, agg, E);
  k_node_mlp<true><<<nb_n128, 256, 0, stream>>>(agg, Bp4, bg1, Bp5, bg2,
                                                Bp6, bnh, nf16, agg, node_out, N);
}

// Round 16
// 362.358 us; speedup vs baseline: 1.1075x; 1.1005x over previous
//
#include <hip/hip_runtime.h>

#define HH 64

typedef __attribute__((ext_vector_type(8))) short bf16x8;
typedef __attribute__((ext_vector_type(16))) float f32x16;
typedef __attribute__((ext_vector_type(4))) unsigned uintx4;

__device__ __forceinline__ unsigned short f2bf(float f) {
  unsigned u = __builtin_bit_cast(unsigned, f);
  return (unsigned short)((u + 0x7FFFu + ((u >> 16) & 1u)) >> 16);
}
__device__ __forceinline__ float bf2f(unsigned short h) {
  unsigned u = ((unsigned)h) << 16;
  return __builtin_bit_cast(float, u);
}
__device__ __forceinline__ unsigned pk2bf(float lo, float hi) {
  unsigned r;
  asm("v_cvt_pk_bf16_f32 %0, %1, %2" : "=v"(r) : "v"(lo), "v"(hi));
  return r;
}

// ---------- prep: Wvo = Wo@Wv, bvo = Wo@bv + bo, B-packs ----------
// EVEN/ODD pack: n = 2*(ln&31) + t ; k = s*16 + (ln>>5)*8 + e8
__global__ __launch_bounds__(256) void k_prep(
    const float* __restrict__ Wg1, const float* __restrict__ Wg2,
    const float* __restrict__ Wnh, const float* __restrict__ Wo,
    const float* __restrict__ Wv,  const float* __restrict__ bv,
    const float* __restrict__ bo,  const float* __restrict__ We2,
    float* __restrict__ Wvo, float* __restrict__ bvo,
    unsigned short* __restrict__ Bp3, unsigned short* __restrict__ Bp4,
    unsigned short* __restrict__ Bp5, unsigned short* __restrict__ Bp6)
{
  int idx = blockIdx.x * 256 + threadIdx.x;
  if (idx < 4096) {
    int j = idx >> 6, k = idx & 63;
    float a = 0.f;
    #pragma unroll 4
    for (int l = 0; l < 64; ++l) a = fmaf(Wo[j * 64 + l], Wv[l * 64 + k], a);
    Wvo[idx] = a;
  }
  if (idx < 64) {
    float a = bo[idx];
    for (int l = 0; l < 64; ++l) a = fmaf(Wo[idx * 64 + l], bv[l], a);
    bvo[idx] = a;
  }
  if (idx < 4096) {
    int e8 = idx & 7, ln = (idx >> 3) & 63, t = (idx >> 9) & 1, s = idx >> 10;
    int n = 2 * (ln & 31) + t;
    int k = s * 16 + (ln >> 5) * 8 + e8;
    Bp3[idx] = f2bf(We2[n * 64 + k]);
    Bp4[idx] = f2bf(Wg1[n * 64 + k]);
    Bp5[idx] = f2bf(Wg2[n * 64 + k]);
  }
  if (idx < 2048) {
    int e8 = idx & 7, ln = (idx >> 3) & 63, s = idx >> 9;
    int n = ln & 31;
    int k = s * 16 + (ln >> 5) * 8 + e8;
    Bp6[idx] = (n < 10) ? f2bf(Wnh[n * 64 + k]) : (unsigned short)0;
  }
}

// ---------- prep2: Wall = Wvo @ Wattn (K=128 pack), ball = Wvo@battn + bvo ----------
__global__ __launch_bounds__(256) void k_prep2(
    const float* __restrict__ Wvo,  const float* __restrict__ bvo,
    const float* __restrict__ Wattn, const float* __restrict__ battn,
    unsigned short* __restrict__ Bpf, float* __restrict__ ball)
{
  int idx = blockIdx.x * 256 + threadIdx.x;
  if (idx < 8192) {
    int e8 = idx & 7, ln = (idx >> 3) & 63, t = (idx >> 9) & 1, s = idx >> 10;
    int n = 2 * (ln & 31) + t;
    int k = s * 16 + (ln >> 5) * 8 + e8;
    float a = 0.f;
    #pragma unroll 4
    for (int l = 0; l < 64; ++l)
      a = fmaf(Wvo[n * 64 + l], Wattn[l * 128 + k], a);
    Bpf[idx] = f2bf(a);
  }
  if (idx < 64) {
    float a = bvo[idx];
    for (int l = 0; l < 64; ++l) a = fmaf(Wvo[idx * 64 + l], battn[l], a);
    ball[idx] = a;
  }
}

// ---------- node init: nf16 + agg(f32) ----------
__global__ __launch_bounds__(256) void k_node_init(
    const float* __restrict__ nl, const float* __restrict__ Wproj,
    const float* __restrict__ bproj, unsigned short* __restrict__ nf16,
    float* __restrict__ agg, int N)
{
  int i = blockIdx.x * 256 + threadIdx.x;
  if (i >= N) return;
  float x[10];
  #pragma unroll
  for (int k = 0; k < 10; ++k) x[k] = nl[(size_t)i * 10 + k];
  const size_t ib = (size_t)i * HH;
  #pragma unroll 1
  for (int j8 = 0; j8 < 8; ++j8) {
    float y[8];
    #pragma unroll
    for (int u = 0; u < 8; ++u) {
      int j = j8 * 8 + u;
      float a = bproj[j];
      #pragma unroll
      for (int k = 0; k < 10; ++k) a = fmaf(x[k], Wproj[j * 10 + k], a);
      y[u] = a;
    }
    uintx4 v = { pk2bf(y[0], y[1]), pk2bf(y[2], y[3]),
                 pk2bf(y[4], y[5]), pk2bf(y[6], y[7]) };
    *(uintx4*)(nf16 + ib + j8 * 8) = v;
    float4 a0 = {y[0], y[1], y[2], y[3]};
    float4 a1 = {y[4], y[5], y[6], y[7]};
    *(float4*)(agg + ib + j8 * 8) = a0;
    *(float4*)(agg + ib + j8 * 8 + 4) = a1;
  }
}

// ---------- CSR build ----------
__global__ __launch_bounds__(256) void k_zero(int* __restrict__ p, int n)
{
  int i = blockIdx.x * 256 + threadIdx.x;
  if (i < n) p[i] = 0;
}

__global__ __launch_bounds__(256) void k_deg(
    const int* __restrict__ ei, int* __restrict__ deg, int E)
{
  int e = blockIdx.x * 256 + threadIdx.x;
  if (e >= E) return;
  atomicAdd(&deg[ei[(size_t)E + e]], 1);
}

__global__ __launch_bounds__(256) void k_part(
    const int* __restrict__ deg, int* __restrict__ bpart, int N)
{
  __shared__ int s[256];
  int t = threadIdx.x;
  int i = blockIdx.x * 256 + t;
  s[t] = (i < N) ? deg[i] : 0;
  __syncthreads();
  #pragma unroll
  for (int o = 128; o > 0; o >>= 1) {
    if (t < o) s[t] += s[t + o];
    __syncthreads();
  }
  if (t == 0) bpart[blockIdx.x] = s[0];
}

__global__ __launch_bounds__(256) void k_scanpart(
    const int* __restrict__ bpart, int* __restrict__ bbase,
    int* __restrict__ rowptr_last, int PB)
{
  __shared__ int s[256];
  int t = threadIdx.x;
  int v = (t < PB) ? bpart[t] : 0;
  s[t] = v;
  __syncthreads();
  for (int o = 1; o < 256; o <<= 1) {
    int u = (t >= o) ? s[t - o] : 0;
    __syncthreads();
    s[t] += u;
    __syncthreads();
  }
  if (t < PB) bbase[t] = s[t] - v;
  if (t == 255) *rowptr_last = s[255];
}

__global__ __launch_bounds__(256) void k_rowptr(
    const int* __restrict__ deg, const int* __restrict__ bbase,
    int* __restrict__ rowptr, int* __restrict__ wofs, int N)
{
  __shared__ int s[256];
  int t = threadIdx.x;
  int i = blockIdx.x * 256 + t;
  int v = (i < N) ? deg[i] : 0;
  s[t] = v;
  __syncthreads();
  for (int o = 1; o < 256; o <<= 1) {
    int u = (t >= o) ? s[t - o] : 0;
    __syncthreads();
    s[t] += u;
    __syncthreads();
  }
  if (i < N) {
    int ex = bbase[blockIdx.x] + s[t] - v;
    rowptr[i] = ex;
    wofs[i]   = ex;
  }
}

// scatter into CSR slots; also materialize el in slot order (el5)
__global__ __launch_bounds__(256) void k_scatter(
    const int* __restrict__ ei, int* __restrict__ wofs,
    const float* __restrict__ el,
    int* __restrict__ eorig, int* __restrict__ srcp, int* __restrict__ dstp,
    float* __restrict__ el5, int E)
{
  int e = blockIdx.x * 256 + threadIdx.x;
  if (e >= E) return;
  int src = ei[e];
  int dst = ei[(size_t)E + e];
  float x0 = el[(size_t)e * 5 + 0], x1 = el[(size_t)e * 5 + 1],
        x2 = el[(size_t)e * 5 + 2], x3 = el[(size_t)e * 5 + 3],
        x4 = el[(size_t)e * 5 + 4];
  int pos = atomicAdd(&wofs[dst], 1);
  eorig[pos] = e;
  srcp[pos]  = src;
  dstp[pos]  = dst;
  float* o = el5 + (size_t)pos * 5;
  o[0] = x0; o[1] = x1; o[2] = x2; o[3] = x3; o[4] = x4;
}

// ---------- fused edge + aggregation kernel ----------
// FIRST: ef0 = We2-MLP(el5) inline (8 MFMA into same acc; no ef read).
// msg GEMM (fused Wall); ef' = relu(base+acc+bias) -> global + m_lds (as q).
// Phase 2 (intra-wave): m = relu(ns_frag + ef') computed from REGISTERS
// (the GEMM1 A-fragments) + LDS — no second nf gather. Block CSR reduction.
// LAST: fused edge head via separate c_lds (reads q).
template <bool FIRST, bool LAST>
__global__ __launch_bounds__(256) void k_edge_agg(
    const unsigned short* __restrict__ nf16, unsigned short* __restrict__ ef16,
    const int* __restrict__ srcp, const int* __restrict__ dstp,
    const int* __restrict__ eorig, const int* __restrict__ rowptr,
    const unsigned short* __restrict__ Bpf, const float* __restrict__ ball,
    const unsigned short* __restrict__ Bp3, const float* __restrict__ be2,
    const float* __restrict__ el5, const float* __restrict__ We1,
    const float* __restrict__ be1,
    const float* __restrict__ Weh, const float* __restrict__ beh,
    float* __restrict__ edge_out, float* __restrict__ agg, int E)
{
  __shared__ unsigned m_lds[128][32];
  __shared__ __align__(16) unsigned short c_lds[LAST ? 4 * 32 * 64 : 4];
  const int tid    = threadIdx.x;
  const int wave   = tid >> 6;
  const int lane   = tid & 63;
  const int er     = lane & 31;
  const int kh     = lane >> 5;
  const int ebase0 = blockIdx.x * 128;
  const int ebase  = ebase0 + wave * 32;

  int p = ebase + er;
  if (p >= E) p = E - 1;
  const int src = srcp[p];
  const int dst = dstp[p];
  const unsigned short* ns = nf16 + (size_t)src * HH;
  const unsigned short* nd = nf16 + (size_t)dst * HH;

  // hoisted reduction indices
  const int lastslot = min(ebase0 + 127, E - 1);
  const int i_lo = dstp[ebase0];
  const int i_hi = dstp[lastslot];

  // src-row fragments: kept live for phase-2 m computation
  bf16x8 nsf[4];
  #pragma unroll
  for (int s = 0; s < 4; ++s)
    nsf[s] = *(const bf16x8*)(ns + s * 16 + kh * 8);

  f32x16 acc0 = {0,0,0,0,0,0,0,0,0,0,0,0,0,0,0,0};
  f32x16 acc1 = {0,0,0,0,0,0,0,0,0,0,0,0,0,0,0,0};

  __builtin_amdgcn_s_setprio(1);

  if (FIRST) {
    const float x0 = el5[(size_t)p * 5 + 0], x1 = el5[(size_t)p * 5 + 1],
                x2 = el5[(size_t)p * 5 + 2], x3 = el5[(size_t)p * 5 + 3],
                x4 = el5[(size_t)p * 5 + 4];
    #pragma unroll
    for (int s = 0; s < 4; ++s) {
      float y[8];
      #pragma unroll
      for (int u = 0; u < 8; ++u) {
        const int k = s * 16 + kh * 8 + u;
        float a = be1[k];
        a = fmaf(x0, We1[k * 5 + 0], a);
        a = fmaf(x1, We1[k * 5 + 1], a);
        a = fmaf(x2, We1[k * 5 + 2], a);
        a = fmaf(x3, We1[k * 5 + 3], a);
        a = fmaf(x4, We1[k * 5 + 4], a);
        y[u] = fmaxf(a, 0.f);
      }
      uintx4 w = { pk2bf(y[0], y[1]), pk2bf(y[2], y[3]),
                   pk2bf(y[4], y[5]), pk2bf(y[6], y[7]) };
      bf16x8 afr = __builtin_bit_cast(bf16x8, w);
      bf16x8 b0 = *(const bf16x8*)(Bp3 + (size_t)((s * 2 + 0) * 64 + lane) * 8);
      bf16x8 b1 = *(const bf16x8*)(Bp3 + (size_t)((s * 2 + 1) * 64 + lane) * 8);
      acc0 = __builtin_amdgcn_mfma_f32_32x32x16_bf16(afr, b0, acc0, 0, 0, 0);
      acc1 = __builtin_amdgcn_mfma_f32_32x32x16_bf16(afr, b1, acc1, 0, 0, 0);
    }
  }

  // msg GEMM: K=128 fused Wall (0-3 from nsf regs, 4-7 from nd)
  #pragma unroll
  for (int s = 0; s < 8; ++s) {
    bf16x8 a;
    if (s < 4) a = nsf[s & 3];
    else       a = *(const bf16x8*)(nd + (s & 3) * 16 + kh * 8);
    bf16x8 b0 = *(const bf16x8*)(Bpf + (size_t)((s * 2 + 0) * 64 + lane) * 8);
    bf16x8 b1 = *(const bf16x8*)(Bpf + (size_t)((s * 2 + 1) * 64 + lane) * 8);
    acc0 = __builtin_amdgcn_mfma_f32_32x32x16_bf16(a, b0, acc0, 0, 0, 0);
    acc1 = __builtin_amdgcn_mfma_f32_32x32x16_bf16(a, b1, acc1, 0, 0, 0);
  }

  __builtin_amdgcn_s_setprio(0);

  // epilogue: ef' = relu(base + acc + bias) -> global store + m_lds (q)
  unsigned* cw32 = (unsigned*)c_lds + wave * 1024;
  const float bt0 = ball[2 * er]     + (FIRST ? be2[2 * er]     : 0.f);
  const float bt1 = ball[2 * er + 1] + (FIRST ? be2[2 * er + 1] : 0.f);
  #pragma unroll
  for (int r = 0; r < 16; ++r) {
    const int m  = (r & 3) + 8 * (r >> 2) + 4 * kh;
    const int eg = ebase + m;
    if (eg < E) {
      float base0 = 0.f, base1 = 0.f;
      if (!FIRST) {
        unsigned old = *((const unsigned*)(ef16 + (size_t)eg * HH) + er);
        base0 = bf2f((unsigned short)(old & 0xffff));
        base1 = bf2f((unsigned short)(old >> 16));
      }
      float x0 = fmaxf(base0 + acc0[r] + bt0, 0.f);
      float x1 = fmaxf(base1 + acc1[r] + bt1, 0.f);
      unsigned q = pk2bf(x0, x1);
      *((unsigned*)(ef16 + (size_t)eg * HH) + er) = q;
      if (LAST)
        cw32[m * 32 + (((er >> 2) ^ (m & 7)) << 2) + (er & 3)] = q;
      const int ls = wave * 32 + m;
      m_lds[ls][er ^ (ls & 31)] = q;     // ef' staged; phase 2 turns it into m
    }
  }

  // phase 2 (intra-wave, rule #18): m = relu(ns_frag + ef') from registers.
  // lane (er,kh) owns slot er's u32 columns c = s*8 + kh*4 + j (bijective
  // across kh halves); nsf[s] u32 j holds features (2c, 2c+1) of the src row.
  asm volatile("s_waitcnt lgkmcnt(0)" ::: "memory");
  __builtin_amdgcn_sched_barrier(0);
  {
    const int ls = wave * 32 + er;
    if (ebase + er < E) {
      #pragma unroll
      for (int s = 0; s < 4; ++s) {
        uintx4 nsu = __builtin_bit_cast(uintx4, nsf[s]);
        #pragma unroll
        for (int j = 0; j < 4; ++j) {
          const int c = s * 8 + kh * 4 + j;
          unsigned q = m_lds[ls][c ^ (ls & 31)];
          unsigned nv = nsu[j];
          float m0 = fmaxf(bf2f((unsigned short)(nv & 0xffff)) +
                           bf2f((unsigned short)(q & 0xffff)), 0.f);
          float m1 = fmaxf(bf2f((unsigned short)(nv >> 16)) +
                           bf2f((unsigned short)(q >> 16)), 0.f);
          m_lds[ls][c ^ (ls & 31)] = pk2bf(m0, m1);
        }
      }
    }
  }

  if (LAST) {
    asm volatile("s_waitcnt lgkmcnt(0)" ::: "memory");
    __builtin_amdgcn_sched_barrier(0);
    if (lane < 32) {
      const int eg = ebase + lane;
      if (eg < E) {
        const unsigned short* cw = c_lds + wave * 2048;
        float a0 = beh[0], a1 = beh[1], a2 = beh[2], a3 = beh[3], a4 = beh[4];
        const int l7 = lane & 7;
        #pragma unroll
        for (int f = 0; f < HH; ++f) {
          float x = bf2f(cw[lane * 64 + (((f >> 3) ^ l7) << 3) + (f & 7)]);
          a0 = fmaf(x, Weh[0 * HH + f], a0);
          a1 = fmaf(x, Weh[1 * HH + f], a1);
          a2 = fmaf(x, Weh[2 * HH + f], a2);
          a3 = fmaf(x, Weh[3 * HH + f], a3);
          a4 = fmaf(x, Weh[4 * HH + f], a4);
        }
        const int eo2 = eorig[eg];
        float* o = edge_out + (size_t)eo2 * 5;
        o[0] = a0; o[1] = a1; o[2] = a2; o[3] = a3; o[4] = a4;
      }
    }
  }

  __syncthreads();

  // block reduction: CSR-contiguous dst runs over this block's 128 slots.
  {
    const int g = tid >> 5;         // 8 groups
    const int l = tid & 31;         // feature pair 2l, 2l+1
    for (int i = i_lo + g; i <= i_hi; i += 8) {
      const int rb = rowptr[i], re = rowptr[i + 1];
      const int lo = max(rb, ebase0);
      const int hi = min(re, ebase0 + 128);
      float s0 = 0.f, s1 = 0.f;
      for (int pp = lo; pp < hi; ++pp) {
        const int ls = pp - ebase0;
        unsigned v = m_lds[ls][l ^ (ls & 31)];
        s0 += bf2f((unsigned short)(v & 0xffff));
        s1 += bf2f((unsigned short)(v >> 16));
      }
      const bool interior = (rb >= ebase0) && (re <= ebase0 + 128);
      if (interior) {
        unsigned nv = *((const unsigned*)(nf16 + (size_t)i * HH) + l);
        float2 o = { bf2f((unsigned short)(nv & 0xffff)) + s0,
                     bf2f((unsigned short)(nv >> 16))    + s1 };
        *(float2*)(agg + (size_t)i * HH + 2 * l) = o;
      } else if (hi > lo) {
        atomicAdd(agg + (size_t)i * HH + 2 * l,     s0);
        atomicAdd(agg + (size_t)i * HH + 2 * l + 1, s1);
      }
    }
  }
}

// ---------- node MLP via MFMA (f32 agg input, even/odd pack) ----------
template <bool LAST>
__global__ __launch_bounds__(256) void k_node_mlp(
    const float* __restrict__ agg,
    const unsigned short* __restrict__ Bp4, const float* __restrict__ bg1,
    const unsigned short* __restrict__ Bp5, const float* __restrict__ bg2,
    const unsigned short* __restrict__ Bp6, const float* __restrict__ bnh,
    unsigned short* __restrict__ nf16, float* __restrict__ aggw,
    float* __restrict__ node_out, int N)
{
  __shared__ __align__(16) unsigned short c_lds[4 * 32 * 64];
  const int tid   = threadIdx.x;
  const int wave  = tid >> 6;
  const int lane  = tid & 63;
  const int er    = lane & 31;
  const int kh    = lane >> 5;
  const int nbase = blockIdx.x * 128 + wave * 32;
  if (nbase >= N) return;

  int node = nbase + er;
  if (node >= N) node = N - 1;
  const float* ar = agg + (size_t)node * HH;

  f32x16 acc0 = {0,0,0,0,0,0,0,0,0,0,0,0,0,0,0,0};
  f32x16 acc1 = {0,0,0,0,0,0,0,0,0,0,0,0,0,0,0,0};
  #pragma unroll
  for (int s = 0; s < 4; ++s) {
    float4 fa = *(const float4*)(ar + s * 16 + kh * 8);
    float4 fb = *(const float4*)(ar + s * 16 + kh * 8 + 4);
    uintx4 w = { pk2bf(fa.x, fa.y), pk2bf(fa.z, fa.w),
                 pk2bf(fb.x, fb.y), pk2bf(fb.z, fb.w) };
    bf16x8 a = __builtin_bit_cast(bf16x8, w);
    bf16x8 b0 = *(const bf16x8*)(Bp4 + (size_t)((s * 2 + 0) * 64 + lane) * 8);
    bf16x8 b1 = *(const bf16x8*)(Bp4 + (size_t)((s * 2 + 1) * 64 + lane) * 8);
    acc0 = __builtin_amdgcn_mfma_f32_32x32x16_bf16(a, b0, acc0, 0, 0, 0);
    acc1 = __builtin_amdgcn_mfma_f32_32x32x16_bf16(a, b1, acc1, 0, 0, 0);
  }

  unsigned short* cw = c_lds + wave * 2048;
  unsigned* cw32 = (unsigned*)cw;
  const float bg10 = bg1[2 * er], bg11 = bg1[2 * er + 1];
  #pragma unroll
  for (int r = 0; r < 16; ++r) {
    const int m = (r & 3) + 8 * (r >> 2) + 4 * kh;
    unsigned q = pk2bf(fmaxf(acc0[r] + bg10, 0.f), fmaxf(acc1[r] + bg11, 0.f));
    cw32[m * 32 + (((er >> 2) ^ (m & 7)) << 2) + (er & 3)] = q;
  }
  asm volatile("s_waitcnt lgkmcnt(0)" ::: "memory");
  __builtin_amdgcn_sched_barrier(0);

  f32x16 d0 = {0,0,0,0,0,0,0,0,0,0,0,0,0,0,0,0};
  f32x16 d1 = {0,0,0,0,0,0,0,0,0,0,0,0,0,0,0,0};
  #pragma unroll
  for (int s = 0; s < 4; ++s) {
    const int g = s * 2 + kh;
    bf16x8 a2 = *(const bf16x8*)(cw + er * 64 + ((g ^ (er & 7)) << 3));
    bf16x8 b0 = *(const bf16x8*)(Bp5 + (size_t)((s * 2 + 0) * 64 + lane) * 8);
    bf16x8 b1 = *(const bf16x8*)(Bp5 + (size_t)((s * 2 + 1) * 64 + lane) * 8);
    d0 = __builtin_amdgcn_mfma_f32_32x32x16_bf16(a2, b0, d0, 0, 0, 0);
    d1 = __builtin_amdgcn_mfma_f32_32x32x16_bf16(a2, b1, d1, 0, 0, 0);
  }

  const float bg20 = bg2[2 * er], bg21 = bg2[2 * er + 1];
  if (!LAST) {
    #pragma unroll
    for (int r = 0; r < 16; ++r) {
      const int m  = (r & 3) + 8 * (r >> 2) + 4 * kh;
      const int ng = nbase + m;
      if (ng < N) {
        float v0 = fmaxf(d0[r] + bg20, 0.f);
        float v1 = fmaxf(d1[r] + bg21, 0.f);
        *((unsigned*)(nf16 + (size_t)ng * HH) + er) = pk2bf(v0, v1);
        float2 o = { v0, v1 };
        *(float2*)(aggw + (size_t)ng * HH + 2 * er) = o;
      }
    }
  } else {
    #pragma unroll
    for (int r = 0; r < 16; ++r) {
      const int m = (r & 3) + 8 * (r >> 2) + 4 * kh;
      unsigned q = pk2bf(fmaxf(d0[r] + bg20, 0.f), fmaxf(d1[r] + bg21, 0.f));
      cw32[m * 32 + (((er >> 2) ^ (m & 7)) << 2) + (er & 3)] = q;
    }
    asm volatile("s_waitcnt lgkmcnt(0)" ::: "memory");
    __builtin_amdgcn_sched_barrier(0);

    f32x16 hacc = {0,0,0,0,0,0,0,0,0,0,0,0,0,0,0,0};
    #pragma unroll
    for (int s = 0; s < 4; ++s) {
      const int g = s * 2 + kh;
      bf16x8 a2 = *(const bf16x8*)(cw + er * 64 + ((g ^ (er & 7)) << 3));
      bf16x8 b = *(const bf16x8*)(Bp6 + (size_t)(s * 64 + lane) * 8);
      hacc = __builtin_amdgcn_mfma_f32_32x32x16_bf16(a2, b, hacc, 0, 0, 0);
    }
    if (er < 10) {
      const float bn = bnh[er];
      #pragma unroll
      for (int r = 0; r < 16; ++r) {
        const int m  = (r & 3) + 8 * (r >> 2) + 4 * kh;
        const int ng = nbase + m;
        if (ng < N) node_out[(size_t)ng * 10 + er] = hacc[r] + bn;
      }
    }
  }
}

extern "C" void kernel_launch(void* const* d_in, const int* in_sizes, int n_in,
                              void* d_out, int out_size, void* d_ws, size_t ws_size,
                              hipStream_t stream)
{
  const float* node_logits = (const float*)d_in[0];
  const float* edge_logits = (const float*)d_in[1];
  const int*   ei          = (const int*)d_in[2];
  const float* Wproj = (const float*)d_in[3];
  const float* bproj = (const float*)d_in[4];
  const float* We1   = (const float*)d_in[5];
  const float* be1   = (const float*)d_in[6];
  const float* We2   = (const float*)d_in[7];
  const float* be2   = (const float*)d_in[8];
  const float* Wg1   = (const float*)d_in[9];
  const float* bg1   = (const float*)d_in[10];
  const float* Wg2   = (const float*)d_in[11];
  const float* bg2   = (const float*)d_in[12];
  const float* Wv    = (const float*)d_in[13];
  const float* bv    = (const float*)d_in[14];
  const float* Wo    = (const float*)d_in[15];
  const float* bo    = (const float*)d_in[16];
  const float* Wattn = (const float*)d_in[17];
  const float* battn = (const float*)d_in[18];
  const float* Wnh   = (const float*)d_in[19];
  const float* bnh   = (const float*)d_in[20];
  const float* Weh   = (const float*)d_in[21];
  const float* beh   = (const float*)d_in[22];

  const int N = in_sizes[0] / 10;
  const int E = in_sizes[1] / 5;

  float* ws = (float*)d_ws;
  size_t off = 0;
  unsigned short* nf16 = (unsigned short*)(ws + off); off += (size_t)N * (HH / 2);
  unsigned short* ef16 = (unsigned short*)(ws + off); off += (size_t)E * (HH / 2);
  float* agg  = ws + off; off += (size_t)N * HH;
  float* Wvo  = ws + off; off += 64 * 64;
  float* bvo  = ws + off; off += 64;
  float* ball = ws + off; off += 64;
  unsigned short* Bpf = (unsigned short*)(ws + off); off += 4096;
  unsigned short* Bp3 = (unsigned short*)(ws + off); off += 2048;
  unsigned short* Bp4 = (unsigned short*)(ws + off); off += 2048;
  unsigned short* Bp5 = (unsigned short*)(ws + off); off += 2048;
  unsigned short* Bp6 = (unsigned short*)(ws + off); off += 1024;
  int* deg    = (int*)(ws + off); off += N;
  int* rowptr = (int*)(ws + off); off += N + 1;
  int* wofs   = (int*)(ws + off); off += N;
  int* eorig  = (int*)(ws + off); off += E;
  int* srcp   = (int*)(ws + off); off += E;
  int* dstp   = (int*)(ws + off); off += E;
  float* el5  = ws + off; off += (size_t)E * 5;
  int* bpart  = (int*)(ws + off); off += 256;
  int* bbase  = (int*)(ws + off); off += 256;

  float* node_out = (float*)d_out;
  float* edge_out = node_out + (size_t)N * 10;

  const int nb_n    = (N + 255) / 256;
  const int nb_e    = (E + 255) / 256;
  const int nb_e128 = (E + 127) / 128;
  const int nb_n128 = (N + 127) / 128;
  const int PB      = (N + 255) / 256;

  k_prep<<<32, 256, 0, stream>>>(Wg1, Wg2, Wnh, Wo, Wv, bv, bo, We2,
                                 Wvo, bvo, Bp3, Bp4, Bp5, Bp6);
  k_prep2<<<32, 256, 0, stream>>>(Wvo, bvo, Wattn, battn, Bpf, ball);
  k_zero<<<nb_n, 256, 0, stream>>>(deg, N);
  k_node_init<<<nb_n, 256, 0, stream>>>(node_logits, Wproj, bproj, nf16, agg, N);
  k_deg<<<nb_e, 256, 0, stream>>>(ei, deg, E);
  k_part<<<PB, 256, 0, stream>>>(deg, bpart, N);
  k_scanpart<<<1, 256, 0, stream>>>(bpart, bbase, rowptr + N, PB);
  k_rowptr<<<PB, 256, 0, stream>>>(deg, bbase, rowptr, wofs, N);
  k_scatter<<<nb_e, 256, 0, stream>>>(ei, wofs, edge_logits, eorig, srcp, dstp,
                                      el5, E);

  // iteration 1 (edge-init fused; agg pre-initialized by k_node_init)
  k_edge_agg<true, false><<<nb_e128, 256, 0, stream>>>(
      nf16, ef16, srcp, dstp, eorig, rowptr, Bpf, ball, Bp3, be2,
      el5, We1, be1, Weh, beh, edge_out, agg, E);
  k_node_mlp<false><<<nb_n128, 256, 0, stream>>>(agg, Bp4, bg1, Bp5, bg2,
                                                 Bp6, bnh, nf16, agg, node_out, N);
  // iteration 2 (agg re-initialized by k_node_mlp<false>)
  k_edge_agg<false, true><<<nb_e128, 256, 0, stream>>>(
      nf16, ef16, srcp, dstp, eorig, rowptr, Bpf, ball, Bp3, be2,
      el5, We1, be1, Weh, beh, edge_out, agg, E);
  k_node_mlp<true><<<nb_n128, 256, 0, stream>>>(agg, Bp4, bg1, Bp5, bg2,
                                                Bp6, bnh, nf16, agg, node_out, N);
}